// Round 4
// baseline (372.443 us; speedup 1.0000x reference)
//
#include <hip/hip_runtime.h>

#define D 256
#define B 128
#define S 64
#define L 32
#define K 32
#define KH 16
#define HSTR 264   // halfword stride for h planes: 264*2B=528B -> bank step 4, 2-way (free)

typedef short bf16x8 __attribute__((ext_vector_type(8)));  // 8 bf16 in 4 VGPRs
typedef float f32x4 __attribute__((ext_vector_type(4)));
typedef unsigned short u16;

__device__ __forceinline__ u16 f2bf(float f) {   // RNE float->bf16 bits
    unsigned u = __float_as_uint(f);
    u += 0x7fffu + ((u >> 16) & 1u);
    return (u16)(u >> 16);
}
__device__ __forceinline__ float bf2f(u16 h) {
    return __uint_as_float(((unsigned)h) << 16);
}

// ---------------------------------------------------------------------------
// sent_mask extraction, robust to bool shipped as 1-byte or int32.
// ---------------------------------------------------------------------------
__global__ void mask_kernel(const void* mraw, int* mask_out) {
    __shared__ int flag;
    const int tid = threadIdx.x;
    if (tid == 0) flag = 0;
    __syncthreads();
    const unsigned int* w32 = (const unsigned int*)mraw;
    int loc = 0;
    for (int i = tid; i < 1024; i += 256)
        if (w32[i] > 1u) loc = 1;
    if (loc) flag = 1;   // benign race
    __syncthreads();
    const bool is_bytes = (flag != 0);
    const unsigned char* b8 = (const unsigned char*)mraw;
    const int* i32 = (const int*)mraw;
    for (int i = tid; i < B * S; i += 256)
        mask_out[i] = is_bytes ? (int)b8[(size_t)i * L] : i32[(size_t)i * L];
}

// ---------------------------------------------------------------------------
// enc = sum_l E[prgrph[...,l]]; emitted directly as bf16 hi/lo planes.
// 4 sentences per block, float4 gathers.
// ---------------------------------------------------------------------------
__global__ __launch_bounds__(256) void embed_kernel(
    const int* __restrict__ prgrph, const float* __restrict__ E,
    u16* __restrict__ enc_hi, u16* __restrict__ enc_lo) {
    const int t = threadIdx.x;
    const int g = t >> 6;                // sentence within block
    const int bs = blockIdx.x * 4 + g;
    const int c4 = t & 63;               // float4 column group
    __shared__ int sidx[4][L];
    if (t < 4 * L) sidx[t >> 5][t & 31] = prgrph[(size_t)blockIdx.x * 4 * L + t];
    __syncthreads();
    const float4* E4 = (const float4*)E;
    float ax = 0.f, ay = 0.f, az = 0.f, aw = 0.f;
    #pragma unroll
    for (int l = 0; l < L; ++l) {
        const float4 v = E4[(size_t)sidx[g][l] * (D / 4) + c4];
        ax += v.x; ay += v.y; az += v.z; aw += v.w;
    }
    const size_t o = (size_t)bs * D + c4 * 4;
    const u16 hx = f2bf(ax), hy = f2bf(ay), hz = f2bf(az), hw = f2bf(aw);
    *(ushort4*)(enc_hi + o) = make_ushort4(hx, hy, hz, hw);
    *(ushort4*)(enc_lo + o) = make_ushort4(
        f2bf(ax - bf2f(hx)), f2bf(ay - bf2f(hy)),
        f2bf(az - bf2f(hz)), f2bf(aw - bf2f(hw)));
}

// ---------------------------------------------------------------------------
// O[r,:] = A[r,:] @ Bm, 32 rows/block, fp32 A (keys@V).
// ---------------------------------------------------------------------------
__global__ __launch_bounds__(256) void gemm_f32_kernel(
    const float* __restrict__ A, const float* __restrict__ Bm,
    float* __restrict__ O) {
    const int row0 = blockIdx.x * 32;
    const int t = threadIdx.x, wave = t >> 6, lane = t & 63;
    __shared__ float a_s[32 * D];
    const float4* Ag = (const float4*)(A + (size_t)row0 * D);
    float4* As4 = (float4*)a_s;
    for (int i = t; i < 32 * D / 4; i += 256) As4[i] = Ag[i];
    __syncthreads();
    const int r0 = wave * 8, c0 = lane * 4;
    float4 acc[8];
    #pragma unroll
    for (int i = 0; i < 8; ++i) acc[i] = make_float4(0.f, 0.f, 0.f, 0.f);
    for (int d = 0; d < D; d += 4) {
        float4 av[8];
        #pragma unroll
        for (int i = 0; i < 8; ++i) av[i] = *(const float4*)&a_s[(r0 + i) * D + d];
        #pragma unroll
        for (int j = 0; j < 4; ++j) {
            const float4 w = *(const float4*)(Bm + (size_t)(d + j) * D + c0);
            #pragma unroll
            for (int i = 0; i < 8; ++i) {
                const float a = (j == 0) ? av[i].x : (j == 1) ? av[i].y
                              : (j == 2) ? av[i].z : av[i].w;
                acc[i].x += a * w.x; acc[i].y += a * w.y;
                acc[i].z += a * w.z; acc[i].w += a * w.w;
            }
        }
    }
    #pragma unroll
    for (int i = 0; i < 8; ++i)
        *(float4*)&O[(size_t)(row0 + r0 + i) * D + c0] = acc[i];
}

// ---------------------------------------------------------------------------
// Same GEMM but A reconstructed from bf16 hi/lo planes (enc @ W).
// ---------------------------------------------------------------------------
__global__ __launch_bounds__(256) void gemm_bf_kernel(
    const u16* __restrict__ Ahi, const u16* __restrict__ Alo,
    const float* __restrict__ Bm, float* __restrict__ O) {
    const int row0 = blockIdx.x * 32;
    const int t = threadIdx.x, wave = t >> 6, lane = t & 63;
    __shared__ float a_s[32 * D];
    const ushort4* Ah4 = (const ushort4*)(Ahi + (size_t)row0 * D);
    const ushort4* Al4 = (const ushort4*)(Alo + (size_t)row0 * D);
    for (int i = t; i < 32 * D / 4; i += 256) {
        const ushort4 h = Ah4[i], l = Al4[i];
        *(float4*)&a_s[i * 4] = make_float4(
            bf2f(h.x) + bf2f(l.x), bf2f(h.y) + bf2f(l.y),
            bf2f(h.z) + bf2f(l.z), bf2f(h.w) + bf2f(l.w));
    }
    __syncthreads();
    const int r0 = wave * 8, c0 = lane * 4;
    float4 acc[8];
    #pragma unroll
    for (int i = 0; i < 8; ++i) acc[i] = make_float4(0.f, 0.f, 0.f, 0.f);
    for (int d = 0; d < D; d += 4) {
        float4 av[8];
        #pragma unroll
        for (int i = 0; i < 8; ++i) av[i] = *(const float4*)&a_s[(r0 + i) * D + d];
        #pragma unroll
        for (int j = 0; j < 4; ++j) {
            const float4 w = *(const float4*)(Bm + (size_t)(d + j) * D + c0);
            #pragma unroll
            for (int i = 0; i < 8; ++i) {
                const float a = (j == 0) ? av[i].x : (j == 1) ? av[i].y
                              : (j == 2) ? av[i].z : av[i].w;
                acc[i].x += a * w.x; acc[i].y += a * w.y;
                acc[i].z += a * w.z; acc[i].w += a * w.w;
            }
        }
    }
    #pragma unroll
    for (int i = 0; i < 8; ++i)
        *(float4*)&O[(size_t)(row0 + r0 + i) * D + c0] = acc[i];
}

// ---------------------------------------------------------------------------
// ek[b,s,k] = enc[b,s,:] . keys[b,k,:]   (gate bias, step-invariant wrt h)
// One block per b; keys[b] staged in LDS (padded stride, conflict-free).
// ---------------------------------------------------------------------------
__global__ __launch_bounds__(256) void ek_kernel(
    const u16* __restrict__ enc_hi, const u16* __restrict__ enc_lo,
    const float* __restrict__ keys, float* __restrict__ ek) {
    const int b = blockIdx.x, t = threadIdx.x;
    __shared__ float ks[K][D + 4];
    const float4* kg = (const float4*)(keys + (size_t)b * K * D);
    for (int i = t; i < K * D / 4; i += 256)
        *(float4*)&ks[i >> 6][(i & 63) * 4] = kg[i];
    __syncthreads();
    const int s = t >> 2, kq = t & 3;          // k = kq + 4j
    const ushort4* eh4 = (const ushort4*)(enc_hi + (size_t)(b * S + s) * D);
    const ushort4* el4 = (const ushort4*)(enc_lo + (size_t)(b * S + s) * D);
    float acc[8];
    #pragma unroll
    for (int j = 0; j < 8; ++j) acc[j] = 0.f;
    for (int d4 = 0; d4 < D / 4; ++d4) {
        const ushort4 h = eh4[d4], l = el4[d4];
        const float e0 = bf2f(h.x) + bf2f(l.x), e1 = bf2f(h.y) + bf2f(l.y);
        const float e2 = bf2f(h.z) + bf2f(l.z), e3 = bf2f(h.w) + bf2f(l.w);
        #pragma unroll
        for (int j = 0; j < 8; ++j) {
            const float4 kv = *(const float4*)&ks[kq + 4 * j][d4 * 4];
            acc[j] += e0 * kv.x + e1 * kv.y + e2 * kv.z + e3 * kv.w;
        }
    }
    #pragma unroll
    for (int j = 0; j < 8; ++j)
        ek[(size_t)(b * S + s) * K + kq + 4 * j] = acc[j];
}

// ---------------------------------------------------------------------------
// Recurrence. Block = (b, 16-row half of K); 4 waves, wave w -> cols [64w,64w+64).
// Lane (n=lane&15, quad=lane>>4). C/D: row=quad*4+reg, col=64w+16sub+n.
// Gate via MFMA: e appended as broadcast B-operand -> acc_e[row]=e.h_prev[row]
// in EVERY wave (no cross-wave reduce, no extra barrier). h double-buffered in
// split bf16 hi/lo LDS planes -> ONE barrier/step, zero unpack VALU. Next
// active step's e-frags/ek/eW prefetched pre-barrier into the same regs.
// NOTE: ek is indexed by ABSOLUTE entity -> must include kh (R3 bug was here).
// ---------------------------------------------------------------------------
__global__ __launch_bounds__(256, 1) void recur_kernel(
    const u16* __restrict__ enc_hi, const u16* __restrict__ enc_lo,
    const float* __restrict__ eWp, const float* __restrict__ keysV,
    const float* __restrict__ ek, const float* __restrict__ U,
    const int* __restrict__ mask, float* __restrict__ out) {
    const int b  = blockIdx.x >> 1;
    const int kh = (blockIdx.x & 1) * KH;
    const int t = threadIdx.x;
    const int wave = t >> 6, lane = t & 63;
    const int n = lane & 15, quad = lane >> 4;

    __shared__ u16 hHi[2][KH][HSTR];     // 2 x 8.4 KB
    __shared__ u16 hLo[2][KH][HSTR];
    __shared__ float redN[2][KH][4];

    // ---- preload U B-fragments (hi/lo), step-invariant -> registers/AGPRs ----
    bf16x8 Uhi[4][8], Ulo[4][8];
    #pragma unroll
    for (int sub = 0; sub < 4; ++sub) {
        const int col = wave * 64 + sub * 16 + n;
        #pragma unroll
        for (int kt = 0; kt < 8; ++kt) {
            #pragma unroll
            for (int j = 0; j < 8; ++j) {
                const int k = kt * 32 + quad * 8 + j;
                const float u = U[(size_t)k * D + col];
                const u16 h16 = f2bf(u);
                Uhi[sub][kt][j] = (short)h16;
                Ulo[sub][kt][j] = (short)f2bf(u - bf2f(h16));
            }
        }
    }

    // ---- per-lane state ----
    float upv[4][4];            // unnormalized h rows; actual h = rn[reg]*upv
    float rn[4];
    float keysVc[4][4];
    #pragma unroll
    for (int reg = 0; reg < 4; ++reg) {
        rn[reg] = 1.f;
        const size_t base = (size_t)(b * K + kh + quad * 4 + reg) * D;
        #pragma unroll
        for (int sub = 0; sub < 4; ++sub) {
            upv[reg][sub] = 0.f;
            keysVc[reg][sub] = keysV[base + wave * 64 + sub * 16 + n];
        }
    }

    // ---- active-step bitmask (uniform across waves) ----
    const int* bm = mask + b * S;
    unsigned long long rem = __ballot(bm[lane & 63] != 0);

    bf16x8 eh[8], el[8];
    float4 ekv;
    float eWc[4];
    if (rem) {      // prefetch first active step
        const int s0 = (int)__builtin_ctzll(rem);
        const size_t eo = (size_t)(b * S + s0) * D;
        #pragma unroll
        for (int kt = 0; kt < 8; ++kt) {
            eh[kt] = *(const bf16x8*)(enc_hi + eo + kt * 32 + quad * 8);
            el[kt] = *(const bf16x8*)(enc_lo + eo + kt * 32 + quad * 8);
        }
        ekv = *(const float4*)(ek + (size_t)(b * S + s0) * K + kh + quad * 4);
        #pragma unroll
        for (int sub = 0; sub < 4; ++sub)
            eWc[sub] = eWp[eo + wave * 64 + sub * 16 + n];
    }

    int p = 0, q = 0;
    bool first = true;
    while (rem) {
        rem &= rem - 1;
        const int sn = rem ? (int)__builtin_ctzll(rem) : -1;

        // ---- MFMA: accU = upv_prev @ U ; accE = upv_prev . e (3-term bf16) ----
        f32x4 accU[4] = {{0.f,0.f,0.f,0.f},{0.f,0.f,0.f,0.f},
                         {0.f,0.f,0.f,0.f},{0.f,0.f,0.f,0.f}};
        f32x4 accE = {0.f,0.f,0.f,0.f};
        if (!first) {
            #pragma unroll
            for (int kt = 0; kt < 8; ++kt) {
                const bf16x8 ahi = *(const bf16x8*)&hHi[p][n][kt * 32 + quad * 8];
                const bf16x8 alo = *(const bf16x8*)&hLo[p][n][kt * 32 + quad * 8];
                accE = __builtin_amdgcn_mfma_f32_16x16x32_bf16(ahi, eh[kt], accE, 0, 0, 0);
                accE = __builtin_amdgcn_mfma_f32_16x16x32_bf16(alo, eh[kt], accE, 0, 0, 0);
                accE = __builtin_amdgcn_mfma_f32_16x16x32_bf16(ahi, el[kt], accE, 0, 0, 0);
                #pragma unroll
                for (int sub = 0; sub < 4; ++sub) {
                    accU[sub] = __builtin_amdgcn_mfma_f32_16x16x32_bf16(ahi, Uhi[sub][kt], accU[sub], 0, 0, 0);
                    accU[sub] = __builtin_amdgcn_mfma_f32_16x16x32_bf16(alo, Uhi[sub][kt], accU[sub], 0, 0, 0);
                    accU[sub] = __builtin_amdgcn_mfma_f32_16x16x32_bf16(ahi, Ulo[sub][kt], accU[sub], 0, 0, 0);
                }
            }
        }

        // ---- gate (wave-local: accE holds full k-sum) ----
        float gate[4];
        #pragma unroll
        for (int reg = 0; reg < 4; ++reg) {
            const float ekb = (reg == 0) ? ekv.x : (reg == 1) ? ekv.y
                            : (reg == 2) ? ekv.z : ekv.w;
            const float g = rn[reg] * accE[reg] + ekb;
            gate[reg] = 1.f / (1.f + __expf(-g));
        }

        // ---- update + split-write new h + norm partial ----
        const int pw = p ^ 1;
        float pn[4];
        #pragma unroll
        for (int reg = 0; reg < 4; ++reg) {
            const int row = quad * 4 + reg;
            float sq = 0.f;
            #pragma unroll
            for (int sub = 0; sub < 4; ++sub) {
                float ht = rn[reg] * accU[sub][reg] + keysVc[reg][sub] + eWc[sub];
                ht = fmaxf(ht, 0.f);
                const float u2 = rn[reg] * upv[reg][sub] + gate[reg] * ht;
                upv[reg][sub] = u2;
                sq += u2 * u2;
                const u16 hi = f2bf(u2);
                const int col = wave * 64 + sub * 16 + n;
                hHi[pw][row][col] = hi;
                hLo[pw][row][col] = f2bf(u2 - bf2f(hi));
            }
            pn[reg] = sq;
        }
        #pragma unroll
        for (int m = 1; m <= 8; m <<= 1) {
            #pragma unroll
            for (int reg = 0; reg < 4; ++reg) pn[reg] += __shfl_xor(pn[reg], m);
        }
        if (n == 0) {
            #pragma unroll
            for (int reg = 0; reg < 4; ++reg) redN[q][quad * 4 + reg][wave] = pn[reg];
        }

        // ---- prefetch next active step (lands during/after barrier) ----
        if (sn >= 0) {
            const size_t eo = (size_t)(b * S + sn) * D;
            #pragma unroll
            for (int kt = 0; kt < 8; ++kt) {
                eh[kt] = *(const bf16x8*)(enc_hi + eo + kt * 32 + quad * 8);
                el[kt] = *(const bf16x8*)(enc_lo + eo + kt * 32 + quad * 8);
            }
            ekv = *(const float4*)(ek + (size_t)(b * S + sn) * K + kh + quad * 4);
            #pragma unroll
            for (int sub = 0; sub < 4; ++sub)
                eWc[sub] = eWp[eo + wave * 64 + sub * 16 + n];
        }

        __syncthreads();   // the ONLY barrier: h writes + redN visible to all

        #pragma unroll
        for (int reg = 0; reg < 4; ++reg) {
            const float4 r4 = *(const float4*)redN[q][quad * 4 + reg];
            rn[reg] = rsqrtf(fmaxf(r4.x + r4.y + r4.z + r4.w, 1e-12f));
        }
        p ^= 1; q ^= 1; first = false;
    }

    #pragma unroll
    for (int reg = 0; reg < 4; ++reg) {
        const size_t base = (size_t)(b * K + kh + quad * 4 + reg) * D;
        #pragma unroll
        for (int sub = 0; sub < 4; ++sub)
            out[base + wave * 64 + sub * 16 + n] = rn[reg] * upv[reg][sub];
    }
}

extern "C" void kernel_launch(void* const* d_in, const int* in_sizes, int n_in,
                              void* d_out, int out_size, void* d_ws, size_t ws_size,
                              hipStream_t stream) {
    const int*   prgrph = (const int*)d_in[0];
    const void*  pmask  = d_in[1];
    const float* keys   = (const float*)d_in[2];
    const float* E      = (const float*)d_in[3];
    const float* U      = (const float*)d_in[4];
    const float* V      = (const float*)d_in[5];
    const float* W      = (const float*)d_in[6];
    float* out = (float*)d_out;

    // workspace layout
    float* ws_eW    = (float*)d_ws;                          // B*S*D fp32   (8 MB)
    float* ws_keysV = ws_eW + (size_t)B * S * D;             // B*K*D fp32   (4 MB)
    float* ws_ek    = ws_keysV + (size_t)B * K * D;          // B*S*K fp32   (1 MB)
    u16*   ws_ehi   = (u16*)(ws_ek + (size_t)B * S * K);     // B*S*D u16    (4 MB)
    u16*   ws_elo   = ws_ehi + (size_t)B * S * D;            // B*S*D u16    (4 MB)
    int*   ws_mask  = (int*)(ws_elo + (size_t)B * S * D);    // B*S int

    mask_kernel<<<1, 256, 0, stream>>>(pmask, ws_mask);
    embed_kernel<<<(B * S) / 4, 256, 0, stream>>>(prgrph, E, ws_ehi, ws_elo);
    gemm_bf_kernel<<<(B * S) / 32, 256, 0, stream>>>(ws_ehi, ws_elo, W, ws_eW);
    gemm_f32_kernel<<<(B * K) / 32, 256, 0, stream>>>(keys, V, ws_keysV);
    ek_kernel<<<B, 256, 0, stream>>>(ws_ehi, ws_elo, keys, ws_ek);
    recur_kernel<<<B * (K / KH), 256, 0, stream>>>(
        ws_ehi, ws_elo, ws_eW, ws_keysV, ws_ek, U, ws_mask, out);
}

// Round 5
// 348.526 us; speedup vs baseline: 1.0686x; 1.0686x over previous
//
#include <hip/hip_runtime.h>

#define D 256
#define B 128
#define S 64
#define L 32
#define K 32
#define KH 16
#define NW 8      // waves per recurrence block (512 threads)
#define NSUB 2    // 16-col sub-tiles per wave (32 cols/wave)
#define HSTR 260  // u16 stride: 520B -> lane addr 8*n+16*q mod 128 -> max 4-way

typedef short bf16x8 __attribute__((ext_vector_type(8)));  // 8 bf16 in 4 VGPRs
typedef float f32x4 __attribute__((ext_vector_type(4)));
typedef unsigned short u16;

__device__ __forceinline__ u16 f2bf(float f) {   // RNE float->bf16 bits
    unsigned u = __float_as_uint(f);
    u += 0x7fffu + ((u >> 16) & 1u);
    return (u16)(u >> 16);
}
__device__ __forceinline__ float bf2f(u16 h) {
    return __uint_as_float(((unsigned)h) << 16);
}

// ---------------------------------------------------------------------------
// sent_mask extraction, robust to bool shipped as 1-byte or int32.
// ---------------------------------------------------------------------------
__global__ void mask_kernel(const void* mraw, int* mask_out) {
    __shared__ int flag;
    const int tid = threadIdx.x;
    if (tid == 0) flag = 0;
    __syncthreads();
    const unsigned int* w32 = (const unsigned int*)mraw;
    int loc = 0;
    for (int i = tid; i < 1024; i += 256)
        if (w32[i] > 1u) loc = 1;
    if (loc) flag = 1;   // benign race
    __syncthreads();
    const bool is_bytes = (flag != 0);
    const unsigned char* b8 = (const unsigned char*)mraw;
    const int* i32 = (const int*)mraw;
    for (int i = tid; i < B * S; i += 256)
        mask_out[i] = is_bytes ? (int)b8[(size_t)i * L] : i32[(size_t)i * L];
}

// ---------------------------------------------------------------------------
// enc_sents[b,s,:] = sum_l E[prgrph[b,s,l], :]  (fp32 out, float4 gathers)
// ---------------------------------------------------------------------------
__global__ __launch_bounds__(256) void embed_kernel(
    const int* __restrict__ prgrph, const float* __restrict__ E,
    float* __restrict__ enc) {
    const int t = threadIdx.x;
    const int g = t >> 6;                // sentence within block
    const int bs = blockIdx.x * 4 + g;
    const int c4 = t & 63;               // float4 column group
    __shared__ int sidx[4][L];
    if (t < 4 * L) sidx[t >> 5][t & 31] = prgrph[(size_t)blockIdx.x * 4 * L + t];
    __syncthreads();
    const float4* E4 = (const float4*)E;
    float4 a = make_float4(0.f, 0.f, 0.f, 0.f);
    #pragma unroll
    for (int l = 0; l < L; ++l) {
        const float4 v = E4[(size_t)sidx[g][l] * (D / 4) + c4];
        a.x += v.x; a.y += v.y; a.z += v.z; a.w += v.w;
    }
    *(float4*)&enc[(size_t)bs * D + c4 * 4] = a;
}

// ---------------------------------------------------------------------------
// O[r,:] = A[r,:] @ Bm, 32 rows/block (enc@W and keys@V).
// ---------------------------------------------------------------------------
__global__ __launch_bounds__(256) void gemm_f32_kernel(
    const float* __restrict__ A, const float* __restrict__ Bm,
    float* __restrict__ O) {
    const int row0 = blockIdx.x * 32;
    const int t = threadIdx.x, wave = t >> 6, lane = t & 63;
    __shared__ float a_s[32 * D];
    const float4* Ag = (const float4*)(A + (size_t)row0 * D);
    float4* As4 = (float4*)a_s;
    for (int i = t; i < 32 * D / 4; i += 256) As4[i] = Ag[i];
    __syncthreads();
    const int r0 = wave * 8, c0 = lane * 4;
    float4 acc[8];
    #pragma unroll
    for (int i = 0; i < 8; ++i) acc[i] = make_float4(0.f, 0.f, 0.f, 0.f);
    for (int d = 0; d < D; d += 4) {
        float4 av[8];
        #pragma unroll
        for (int i = 0; i < 8; ++i) av[i] = *(const float4*)&a_s[(r0 + i) * D + d];
        #pragma unroll
        for (int j = 0; j < 4; ++j) {
            const float4 w = *(const float4*)(Bm + (size_t)(d + j) * D + c0);
            #pragma unroll
            for (int i = 0; i < 8; ++i) {
                const float a = (j == 0) ? av[i].x : (j == 1) ? av[i].y
                              : (j == 2) ? av[i].z : av[i].w;
                acc[i].x += a * w.x; acc[i].y += a * w.y;
                acc[i].z += a * w.z; acc[i].w += a * w.w;
            }
        }
    }
    #pragma unroll
    for (int i = 0; i < 8; ++i)
        *(float4*)&O[(size_t)(row0 + r0 + i) * D + c0] = acc[i];
}

// ---------------------------------------------------------------------------
// ek[b,s,k] = enc[b,s,:] . keys[b,k,:]
// ---------------------------------------------------------------------------
__global__ __launch_bounds__(256) void ek_kernel(
    const float* __restrict__ enc, const float* __restrict__ keys,
    float* __restrict__ ek) {
    const int b = blockIdx.x, t = threadIdx.x;
    __shared__ float ks[K][D + 4];
    const float4* kg = (const float4*)(keys + (size_t)b * K * D);
    for (int i = t; i < K * D / 4; i += 256)
        *(float4*)&ks[i >> 6][(i & 63) * 4] = kg[i];
    __syncthreads();
    const int s = t >> 2, kq = t & 3;          // k = kq + 4j
    const float4* e4 = (const float4*)(enc + (size_t)(b * S + s) * D);
    float acc[8];
    #pragma unroll
    for (int j = 0; j < 8; ++j) acc[j] = 0.f;
    for (int d4 = 0; d4 < D / 4; ++d4) {
        const float4 e = e4[d4];
        #pragma unroll
        for (int j = 0; j < 8; ++j) {
            const float4 kv = *(const float4*)&ks[kq + 4 * j][d4 * 4];
            acc[j] += e.x * kv.x + e.y * kv.y + e.z * kv.z + e.w * kv.w;
        }
    }
    #pragma unroll
    for (int j = 0; j < 8; ++j)
        ek[(size_t)(b * S + s) * K + kq + 4 * j] = acc[j];
}

// ---------------------------------------------------------------------------
// Recurrence. Block = (b, 16-row half of K); 512 threads = 8 waves; wave w
// owns cols [32w, 32w+32) = 2 MFMA sub-tiles. Lane (n=lane&15, quad=lane>>4).
// C/D: row=quad*4+reg, col=32w+16sub+n. U hi/lo B-frags in regs (128 VGPR).
// Gate dot e_s.h_{s-1}: computed in fp32 VALU at END of prev step against
// prefetched e_next (upv is h unnormalized in regs), shuffle-reduced over n,
// 8 wave-partials -> LDS redG, summed post-barrier next step. No accE MFMAs,
// no e-fragments -> fits 256 regs/wave -> 2 waves/SIMD, no spill.
// ONE barrier/step; h double-buffered bf16 hi/lo planes in LDS.
// ---------------------------------------------------------------------------
__global__ __launch_bounds__(512, 2) void recur_kernel(
    const float* __restrict__ enc, const float* __restrict__ eWp,
    const float* __restrict__ keysV, const float* __restrict__ ek,
    const float* __restrict__ U, const int* __restrict__ mask,
    float* __restrict__ out) {
    const int b  = blockIdx.x >> 1;
    const int kh = (blockIdx.x & 1) * KH;
    const int t = threadIdx.x;
    const int wave = t >> 6, lane = t & 63;
    const int n = lane & 15, quad = lane >> 4;

    __shared__ u16 hHi[2][KH][HSTR];     // 2 x 8.1 KB
    __shared__ u16 hLo[2][KH][HSTR];
    __shared__ float redN[2][KH][NW];    // norm partials per wave
    __shared__ float redG[2][KH][NW];    // gate-dot partials per wave

    // ---- preload U B-fragments (hi/lo): 2 subs x 8 kt -> 128 VGPRs ----
    bf16x8 Uhi[NSUB][8], Ulo[NSUB][8];
    #pragma unroll
    for (int sub = 0; sub < NSUB; ++sub) {
        const int col = wave * 32 + sub * 16 + n;
        #pragma unroll
        for (int kt = 0; kt < 8; ++kt) {
            #pragma unroll
            for (int j = 0; j < 8; ++j) {
                const int k = kt * 32 + quad * 8 + j;
                const float u = U[(size_t)k * D + col];
                const u16 h16 = f2bf(u);
                Uhi[sub][kt][j] = (short)h16;
                Ulo[sub][kt][j] = (short)f2bf(u - bf2f(h16));
            }
        }
    }

    // ---- per-lane state ----
    float upv[4][NSUB];          // unnormalized h rows; actual h = rn[reg]*upv
    float rn[4];
    float keysVc[4][NSUB];
    #pragma unroll
    for (int reg = 0; reg < 4; ++reg) {
        rn[reg] = 1.f;
        const size_t base = (size_t)(b * K + kh + quad * 4 + reg) * D;
        #pragma unroll
        for (int sub = 0; sub < NSUB; ++sub) {
            upv[reg][sub] = 0.f;
            keysVc[reg][sub] = keysV[base + wave * 32 + sub * 16 + n];
        }
    }

    // ---- active-step bitmask (uniform across waves) ----
    const int* bm = mask + b * S;
    unsigned long long rem = __ballot(bm[lane & 63] != 0);

    float eWc[NSUB];
    float4 ekv;
    if (rem) {      // prefetch first active step (e itself not needed: h=0)
        const int s0 = (int)__builtin_ctzll(rem);
        const size_t eo = (size_t)(b * S + s0) * D;
        #pragma unroll
        for (int sub = 0; sub < NSUB; ++sub)
            eWc[sub] = eWp[eo + wave * 32 + sub * 16 + n];
        ekv = *(const float4*)(ek + (size_t)(b * S + s0) * K + kh + quad * 4);
    }

    int p = 0, q = 0;
    bool first = true;
    while (rem) {
        rem &= rem - 1;
        const int sn = rem ? (int)__builtin_ctzll(rem) : -1;

        // ---- issue next-step loads early (cover latency with MFMA) ----
        float e_n[NSUB], eWn[NSUB];
        float4 ekn;
        if (sn >= 0) {
            const size_t eo = (size_t)(b * S + sn) * D;
            #pragma unroll
            for (int sub = 0; sub < NSUB; ++sub) {
                e_n[sub] = enc[eo + wave * 32 + sub * 16 + n];
                eWn[sub] = eWp[eo + wave * 32 + sub * 16 + n];
            }
            ekn = *(const float4*)(ek + (size_t)(b * S + sn) * K + kh + quad * 4);
        }

        // ---- MFMA: acc = upv_prev @ U (3-term bf16 split, 6 indep chains) ----
        f32x4 acc[NSUB][3];
        #pragma unroll
        for (int sub = 0; sub < NSUB; ++sub)
            #pragma unroll
            for (int c = 0; c < 3; ++c) acc[sub][c] = (f32x4){0.f, 0.f, 0.f, 0.f};
        if (!first) {
            #pragma unroll
            for (int kt = 0; kt < 8; ++kt) {
                const bf16x8 ahi = *(const bf16x8*)&hHi[p][n][kt * 32 + quad * 8];
                const bf16x8 alo = *(const bf16x8*)&hLo[p][n][kt * 32 + quad * 8];
                #pragma unroll
                for (int sub = 0; sub < NSUB; ++sub) {
                    acc[sub][0] = __builtin_amdgcn_mfma_f32_16x16x32_bf16(ahi, Uhi[sub][kt], acc[sub][0], 0, 0, 0);
                    acc[sub][1] = __builtin_amdgcn_mfma_f32_16x16x32_bf16(alo, Uhi[sub][kt], acc[sub][1], 0, 0, 0);
                    acc[sub][2] = __builtin_amdgcn_mfma_f32_16x16x32_bf16(ahi, Ulo[sub][kt], acc[sub][2], 0, 0, 0);
                }
            }
        }

        // ---- gate: logit = rn * sum_w redG + ek  (dot done last step) ----
        float gate[4];
        #pragma unroll
        for (int reg = 0; reg < 4; ++reg) {
            const float ekb = (reg == 0) ? ekv.x : (reg == 1) ? ekv.y
                            : (reg == 2) ? ekv.z : ekv.w;
            float g = ekb;
            if (!first) {
                const float* rg = redG[q ^ 1][quad * 4 + reg];
                const float4 g0 = *(const float4*)rg;
                const float4 g1 = *(const float4*)(rg + 4);
                g += rn[reg] * (g0.x + g0.y + g0.z + g0.w +
                                g1.x + g1.y + g1.z + g1.w);
            }
            gate[reg] = 1.f / (1.f + __expf(-g));
        }

        // ---- update + split-write new h + norm partial ----
        const int pw = p ^ 1;
        float pn[4];
        #pragma unroll
        for (int reg = 0; reg < 4; ++reg) {
            const int row = quad * 4 + reg;
            float sq = 0.f;
            #pragma unroll
            for (int sub = 0; sub < NSUB; ++sub) {
                const float asum = acc[sub][0][reg] + acc[sub][1][reg] + acc[sub][2][reg];
                float ht = rn[reg] * asum + keysVc[reg][sub] + eWc[sub];
                ht = fmaxf(ht, 0.f);
                const float u2 = rn[reg] * upv[reg][sub] + gate[reg] * ht;
                upv[reg][sub] = u2;
                sq += u2 * u2;
                const u16 hi = f2bf(u2);
                const int col = wave * 32 + sub * 16 + n;
                hHi[pw][row][col] = hi;
                hLo[pw][row][col] = f2bf(u2 - bf2f(hi));
            }
            pn[reg] = sq;
        }

        // ---- gate-dot partial for NEXT step: upv_new . e_next (fp32) ----
        float gd[4];
        #pragma unroll
        for (int reg = 0; reg < 4; ++reg) {
            float v = 0.f;
            if (sn >= 0) {
                #pragma unroll
                for (int sub = 0; sub < NSUB; ++sub)
                    v += upv[reg][sub] * e_n[sub];
            }
            gd[reg] = v;
        }
        #pragma unroll
        for (int m = 1; m <= 8; m <<= 1) {
            #pragma unroll
            for (int reg = 0; reg < 4; ++reg) {
                pn[reg] += __shfl_xor(pn[reg], m);
                gd[reg] += __shfl_xor(gd[reg], m);
            }
        }
        if (n == 0) {
            #pragma unroll
            for (int reg = 0; reg < 4; ++reg) {
                redN[q][quad * 4 + reg][wave] = pn[reg];
                redG[q][quad * 4 + reg][wave] = gd[reg];
            }
        }

        __syncthreads();   // the ONLY barrier

        #pragma unroll
        for (int reg = 0; reg < 4; ++reg) {
            const float* rp = redN[q][quad * 4 + reg];
            const float4 r0 = *(const float4*)rp;
            const float4 r1 = *(const float4*)(rp + 4);
            rn[reg] = rsqrtf(fmaxf(r0.x + r0.y + r0.z + r0.w +
                                   r1.x + r1.y + r1.z + r1.w, 1e-12f));
        }
        #pragma unroll
        for (int sub = 0; sub < NSUB; ++sub) eWc[sub] = eWn[sub];
        ekv = ekn;
        p ^= 1; q ^= 1; first = false;
    }

    #pragma unroll
    for (int reg = 0; reg < 4; ++reg) {
        const size_t base = (size_t)(b * K + kh + quad * 4 + reg) * D;
        #pragma unroll
        for (int sub = 0; sub < NSUB; ++sub)
            out[base + wave * 32 + sub * 16 + n] = rn[reg] * upv[reg][sub];
    }
}

extern "C" void kernel_launch(void* const* d_in, const int* in_sizes, int n_in,
                              void* d_out, int out_size, void* d_ws, size_t ws_size,
                              hipStream_t stream) {
    const int*   prgrph = (const int*)d_in[0];
    const void*  pmask  = d_in[1];
    const float* keys   = (const float*)d_in[2];
    const float* E      = (const float*)d_in[3];
    const float* U      = (const float*)d_in[4];
    const float* V      = (const float*)d_in[5];
    const float* W      = (const float*)d_in[6];
    float* out = (float*)d_out;

    // workspace layout (fp32 unless noted)
    float* ws_enc   = (float*)d_ws;                          // B*S*D  (8 MB)
    float* ws_eW    = ws_enc + (size_t)B * S * D;            // B*S*D  (8 MB)
    float* ws_keysV = ws_eW  + (size_t)B * S * D;            // B*K*D  (4 MB)
    float* ws_ek    = ws_keysV + (size_t)B * K * D;          // B*S*K  (1 MB)
    int*   ws_mask  = (int*)(ws_ek + (size_t)B * S * K);     // B*S

    mask_kernel<<<1, 256, 0, stream>>>(pmask, ws_mask);
    embed_kernel<<<(B * S) / 4, 256, 0, stream>>>(prgrph, E, ws_enc);
    gemm_f32_kernel<<<(B * S) / 32, 256, 0, stream>>>(ws_enc, W, ws_eW);
    gemm_f32_kernel<<<(B * K) / 32, 256, 0, stream>>>(keys, V, ws_keysV);
    ek_kernel<<<B, 256, 0, stream>>>(ws_enc, keys, ws_ek);
    recur_kernel<<<B * (K / KH), 512, 0, stream>>>(
        ws_enc, ws_eW, ws_keysV, ws_ek, U, ws_mask, out);
}